// Round 6
// baseline (894.536 us; speedup 1.0000x reference)
//
#include <hip/hip_runtime.h>
#include <math.h>

constexpr int NROWS = 32768;   // B
constexpr int DIMC  = 256;     // D
constexpr int KC    = 4096;    // K

typedef __attribute__((ext_vector_type(8))) short short8;
typedef __attribute__((ext_vector_type(4))) float f32x4;

#define AS1 __attribute__((address_space(1)))
#define AS3 __attribute__((address_space(3)))

struct alignas(16) Part { float d1; int i1; float d2; int i2; };

__device__ __forceinline__ unsigned short f2bf(float x) {
  unsigned u = __float_as_uint(x);
  return (unsigned short)((u + 0x7fffu + ((u >> 16) & 1u)) >> 16);
}

// ---------------------------------------------------------------------------
// Pre-pass: h-plane bf16 in the GEMM's tiled, swizzled HBM layout
// [blk128][kblk(8)][granule g=r*4+slot, 16B], slot holds octet s8=slot^((r>>1)&3).
// (Validated rounds 3-5: SQ_LDS_BANK_CONFLICT = 0 in vq_mfma.)
// ---------------------------------------------------------------------------
__global__ __launch_bounds__(256)
void vq_split(const float* __restrict__ X, unsigned short* __restrict__ out) {
  const int blk = blockIdx.x >> 3;
  const int kb  = blockIdx.x & 7;
  const int t = threadIdx.x;
#pragma unroll
  for (int gi = 0; gi < 2; ++gi) {
    const int g = t + gi * 256;
    const int r = g >> 2, slot = g & 3;
    const int s8 = slot ^ ((r >> 1) & 3);
    const float* src = X + (size_t)(blk * 128 + r) * DIMC + kb * 32 + s8 * 8;
    short8 vh;
#pragma unroll
    for (int j = 0; j < 8; ++j) vh[j] = (short)f2bf(src[j]);
    *(short8*)(out + ((size_t)blk * 8 + kb) * 4096 + g * 8) = vh;
  }
}

// ---------------------------------------------------------------------------
__global__ __launch_bounds__(256)
void vq_rownorm(const float* __restrict__ Z, float* __restrict__ anorm) {
  const int lane = threadIdx.x & 63;
  const int wv   = threadIdx.x >> 6;
  const int row  = blockIdx.x * 4 + wv;
  const float4 z4 = *(const float4*)(Z + (size_t)row * DIMC + lane * 4);
  double s = (double)z4.x * z4.x + (double)z4.y * z4.y +
             (double)z4.z * z4.z + (double)z4.w * z4.w;
#pragma unroll
  for (int off = 32; off > 0; off >>= 1) s += __shfl_down(s, off);
  if (lane == 0) anorm[row] = (float)s;
}

// ---------------------------------------------------------------------------
// Main: h-only bf16 MFMA GEMM (approx dot), 128x128 tiles, 16 KB LDS.
// Fused per-(row, colblock) exact top-2 of d = a - 2f*dot.  (validated r5)
// ---------------------------------------------------------------------------
__global__ __launch_bounds__(256, 4)
void vq_mfma(const unsigned short* __restrict__ Zh, const unsigned short* __restrict__ Wh,
             const float* __restrict__ anorm, Part* __restrict__ partial) {
  __shared__ char lds[16384];          // A: [0,8K), B: [8K,16K)
  const int t = threadIdx.x, lane = t & 63, w = t >> 6;
  const int rb = blockIdx.x >> 5, cb = blockIdx.x & 31;
  const int q = lane >> 4, ml = lane & 15;
  const int wr = w >> 1, wc = w & 1;

  const unsigned short* src0 = (w < 2) ? Zh + (size_t)rb * 32768
                                       : Wh + (size_t)cb * 32768;
  const int half = w & 1;
  char* ldsdst = lds + (w >> 1) * 8192 + half * 4096;

  int aoff[4], boff[4];
#pragma unroll
  for (int i = 0; i < 4; ++i) {
    const int r = wr * 64 + i * 16 + ml;
    aoff[i] = (r * 4 + (q ^ ((r >> 1) & 3))) * 16;
    const int c = wc * 64 + i * 16 + ml;
    boff[i] = (c * 4 + (q ^ ((c >> 1) & 3))) * 16;
  }

  f32x4 acc[4][4];
#pragma unroll
  for (int i = 0; i < 4; ++i)
#pragma unroll
    for (int j = 0; j < 4; ++j) acc[i][j] = (f32x4){0.f, 0.f, 0.f, 0.f};

  for (int kb = 0; kb < 8; ++kb) {
    __syncthreads();
    const unsigned short* s = src0 + kb * 4096 + half * 2048 + lane * 8;
#pragma unroll
    for (int i = 0; i < 4; ++i)
      __builtin_amdgcn_global_load_lds((const AS1 void*)(s + i * 512),
                                       (AS3 void*)(ldsdst + i * 1024), 16, 0, 0);
    __syncthreads();
    short8 Ah[4], Bh[4];
#pragma unroll
    for (int i = 0; i < 4; ++i) {
      Ah[i] = *(const short8*)(lds +        aoff[i]);
      Bh[i] = *(const short8*)(lds + 8192 + boff[i]);
    }
#pragma unroll
    for (int i = 0; i < 4; ++i)
#pragma unroll
      for (int j = 0; j < 4; ++j)
        acc[i][j] = __builtin_amdgcn_mfma_f32_16x16x32_bf16(Ah[i], Bh[j], acc[i][j], 0, 0, 0);
  }

  __syncthreads();
  float* pd1 = (float*)lds;
  int*   pi1 = (int*)(lds + 1024);
  float* pd2 = (float*)(lds + 2048);
  const float INF = 3.4e38f;

#pragma unroll
  for (int i = 0; i < 4; ++i) {
#pragma unroll
    for (int r = 0; r < 4; ++r) {
      const int lr = i * 16 + q * 4 + r;
      const float am = anorm[rb * 128 + wr * 64 + lr];
      float d1m = INF, d2m = INF; int i1m = 0x7fffffff;
#pragma unroll
      for (int j = 0; j < 4; ++j) {
        const float d = am - 2.0f * acc[i][j][r];
        const int idx = cb * 128 + wc * 64 + j * 16 + ml;
        if (d < d1m || (d == d1m && idx < i1m)) { d2m = d1m; d1m = d; i1m = idx; }
        else d2m = fminf(d2m, d);
      }
#pragma unroll
      for (int mask = 1; mask < 16; mask <<= 1) {
        const float od1 = __shfl_xor(d1m, mask);
        const int   oi1 = __shfl_xor(i1m, mask);
        const float od2 = __shfl_xor(d2m, mask);
        if (od1 < d1m || (od1 == d1m && oi1 < i1m)) {
          d2m = fminf(d1m, od2); d1m = od1; i1m = oi1;
        } else d2m = fminf(d2m, od1);
      }
      if (ml == 0) { pd1[w * 64 + lr] = d1m; pi1[w * 64 + lr] = i1m; pd2[w * 64 + lr] = d2m; }
    }
  }
  __syncthreads();
  if (t < 128) {
    const int wrh = t >> 6, lr = t & 63;
    const int e0 = (wrh * 2 + 0) * 64 + lr, e1 = (wrh * 2 + 1) * 64 + lr;
    const float d1a = pd1[e0], d2a = pd2[e0]; const int i1a = pi1[e0];
    const float d1b = pd1[e1], d2b = pd2[e1]; const int i1b = pi1[e1];
    Part p;
    if (d1b < d1a || (d1b == d1a && i1b < i1a)) { p.d1 = d1b; p.i1 = i1b; p.d2 = fminf(d1a, d2b); }
    else                                        { p.d1 = d1a; p.i1 = i1a; p.d2 = fminf(d1b, d2a); }
    p.i2 = 0;
    const int row = rb * 128 + wrh * 64 + lr;
    partial[(size_t)row * 32 + cb] = p;
  }
}

// ---------------------------------------------------------------------------
// Exact np-semantics distance: ascending-dim fp32 fmaf chain (byte-identical
// to the rescue chain validated in rounds 2-5), d = fp32(a - 2f*dot).
// ---------------------------------------------------------------------------
__device__ __forceinline__ float exact_d(const float* __restrict__ Z,
                                         const float* __restrict__ W,
                                         int row, int c, float a) {
  const float* z = Z + (size_t)row * DIMC;
  const float* w = W + (size_t)c * DIMC;
  float dot = 0.f;
  for (int d0 = 0; d0 < DIMC; d0 += 4) {
    const float4 zv = *(const float4*)(z + d0);
    const float4 wv = *(const float4*)(w + d0);
    dot = fmaf(zv.x, wv.x, dot);
    dot = fmaf(zv.y, wv.y, dot);
    dot = fmaf(zv.z, wv.z, dot);
    dot = fmaf(zv.w, wv.w, dot);
  }
  return a - 2.0f * dot;
}

// ---------------------------------------------------------------------------
// Rescue v3: candidate-based exact argmin, one wave per row (all rows).
// thr = m + 2*e_d + bin + slack with rigorous CS bound
// e_d <= 2^-6*1.01*||z||*||w||max, ||w||max = 16*2.44e-4 -> coeff 1.24e-4.
// Codes beyond a colblock's top-2 have d_ap >= d2 (exact 2nd-min), so a
// full 128-code scan is needed only when d2 <= thr.
// ---------------------------------------------------------------------------
__global__ __launch_bounds__(256)
void vq_rescue(const float* __restrict__ Z, const float* __restrict__ W,
               const float* __restrict__ anorm, const Part* __restrict__ partial,
               int* __restrict__ idxbuf) {
  const int lane = threadIdx.x & 63, wv = threadIdx.x >> 6;
  const int row = blockIdx.x * 4 + wv;
  const float INF = 3.4e38f;

  float d1 = INF, d2 = INF; int i1 = 0;
  if (lane < 32) {
    const Part p = partial[(size_t)row * 32 + lane];
    d1 = p.d1; d2 = p.d2; i1 = p.i1;
  }
  float m = d1;
#pragma unroll
  for (int mask = 1; mask < 64; mask <<= 1) m = fminf(m, __shfl_xor(m, mask));
  const float a = anorm[row];
  const float thr = m + (sqrtf(a) * 1.3e-4f + 1.0e-4f);

  float bd = INF; int bi = 0x7fffffff;
  const bool scan   = (lane < 32) && (d2 <= thr);
  const bool single = (lane < 32) && !scan && (d1 <= thr);
  if (single) {
    const float d = exact_d(Z, W, row, i1, a);
    if (d < bd || (d == bd && i1 < bi)) { bd = d; bi = i1; }
  }
  unsigned long long msk = __ballot(scan);
  while (msk) {
    const int cbk = __ffsll(msk) - 1; msk &= msk - 1;
#pragma unroll
    for (int h = 0; h < 2; ++h) {
      const int c = cbk * 128 + h * 64 + lane;
      const float d = exact_d(Z, W, row, c, a);
      if (d < bd || (d == bd && c < bi)) { bd = d; bi = c; }
    }
  }
#pragma unroll
  for (int mask = 1; mask < 64; mask <<= 1) {
    const float od = __shfl_xor(bd, mask);
    const int   oi = __shfl_xor(bi, mask);
    if (od < bd || (od == bd && oi < bi)) { bd = od; bi = oi; }
  }
  if (lane == 0) idxbuf[row] = bi;
}

// ---------------------------------------------------------------------------
__global__ __launch_bounds__(256)
void vq_select(const float* __restrict__ Z, const float* __restrict__ W,
               const int* __restrict__ idxbuf, float* __restrict__ zq_out,
               float* __restrict__ idx_out, double* __restrict__ loss_acc,
               int* __restrict__ hist) {
  __shared__ double sh[4];
  const int lane = threadIdx.x & 63;
  const int wv   = threadIdx.x >> 6;
  const int row  = blockIdx.x * 4 + wv;

  const int k = idxbuf[row];
  const float4 z4 = *(const float4*)(Z + (size_t)row * DIMC + lane * 4);
  const float4 w4 = *(const float4*)(W + (size_t)k   * DIMC + lane * 4);
  *(float4*)(zq_out + (size_t)row * DIMC + lane * 4) = w4;

  const double dx = (double)w4.x - (double)z4.x;
  const double dy = (double)w4.y - (double)z4.y;
  const double dz = (double)w4.z - (double)z4.z;
  const double dw = (double)w4.w - (double)z4.w;
  double l = dx * dx + dy * dy + dz * dz + dw * dw;
#pragma unroll
  for (int off = 32; off > 0; off >>= 1) l += __shfl_down(l, off);

  if (lane == 0) { sh[wv] = l; idx_out[row] = (float)k; atomicAdd(&hist[k], 1); }
  __syncthreads();
  if (threadIdx.x == 0) unsafeAtomicAdd(loss_acc, sh[0] + sh[1] + sh[2] + sh[3]);
}

__global__ __launch_bounds__(64)
void vq_final(const double* __restrict__ loss_acc, const int* __restrict__ hist,
              float* __restrict__ scal) {
  const int lane = threadIdx.x;
  double H = 0.0;
  for (int k = lane; k < KC; k += 64) {
    const double p = (double)hist[k] / (double)NROWS;
    H -= p * log(p + 1e-10);
  }
#pragma unroll
  for (int off = 32; off > 0; off >>= 1) H += __shfl_down(H, off);
  if (lane == 0) {
    scal[0] = (float)(loss_acc[0] * 1.25 / ((double)NROWS * (double)DIMC));
    scal[1] = (float)exp(H);
  }
}

// ---------------------------------------------------------------------------
extern "C" void kernel_launch(void* const* d_in, const int* in_sizes, int n_in,
                              void* d_out, int out_size, void* d_ws, size_t ws_size,
                              hipStream_t stream) {
  const float* Z = (const float*)d_in[0];
  const float* W = (const float*)d_in[1];
  float* out = (float*)d_out;
  float* zq_out  = out;
  float* idx_out = out + (size_t)NROWS * DIMC;
  float* scal    = idx_out + NROWS;

  char* ws = (char*)d_ws;
  double* loss_acc   = (double*)ws;                       // 8 B @0
  int*    hist       = (int*)(ws + 1024);                 // 16 KB
  int*    idxbuf     = (int*)(ws + 32768);                // 128 KB
  float*  anorm      = (float*)(ws + 163840);             // 128 KB
  Part*   partial    = (Part*)(ws + 1048576);             // 16 MB @ 1 MB
  unsigned short* Zh = (unsigned short*)(ws + 20971520);  // 16 MB @ 20 MB
  unsigned short* Wh = (unsigned short*)(ws + 37748736);  // 2 MB  @ 36 MB

  hipMemsetAsync(ws, 0, 17408, stream);                   // loss + hist
  vq_split<<<2048, 256, 0, stream>>>(Z, Zh);
  vq_split<<<256, 256, 0, stream>>>(W, Wh);
  vq_rownorm<<<NROWS / 4, 256, 0, stream>>>(Z, anorm);
  vq_mfma<<<8192, 256, 0, stream>>>(Zh, Wh, anorm, partial);
  vq_rescue<<<NROWS / 4, 256, 0, stream>>>(Z, W, anorm, partial, idxbuf);
  vq_select<<<NROWS / 4, 256, 0, stream>>>(Z, W, idxbuf, zq_out, idx_out, loss_acc, hist);
  vq_final<<<1, 64, 0, stream>>>(loss_acc, hist, scal);
}

// Round 7
// 470.092 us; speedup vs baseline: 1.9029x; 1.9029x over previous
//
#include <hip/hip_runtime.h>
#include <math.h>

constexpr int NROWS = 32768;   // B
constexpr int DIMC  = 256;     // D
constexpr int KC    = 4096;    // K

typedef __attribute__((ext_vector_type(8))) short short8;
typedef __attribute__((ext_vector_type(4))) float f32x4;

#define AS1 __attribute__((address_space(1)))
#define AS3 __attribute__((address_space(3)))

struct alignas(16) Part { float d1; int i1; float d2; int i2; };

// ambiguity window: ~15 sigma of the h-only bf16 approx error (sigma ~ 2e-5
// in d-units), covering 2*e per comparison + accumulation-order slack.
#define WIN 3.0e-4f

__device__ __forceinline__ unsigned short f2bf(float x) {
  unsigned u = __float_as_uint(x);
  return (unsigned short)((u + 0x7fffu + ((u >> 16) & 1u)) >> 16);
}

// ---------------------------------------------------------------------------
// Pre-pass: h-plane bf16 in the GEMM's tiled, swizzled HBM layout
// [blk128][kblk(8)][granule g=r*4+slot, 16B], slot holds octet s8=slot^((r>>1)&3).
// (Validated rounds 3-6: SQ_LDS_BANK_CONFLICT = 0 in vq_mfma.)
// ---------------------------------------------------------------------------
__global__ __launch_bounds__(256)
void vq_split(const float* __restrict__ X, unsigned short* __restrict__ out) {
  const int blk = blockIdx.x >> 3;
  const int kb  = blockIdx.x & 7;
  const int t = threadIdx.x;
#pragma unroll
  for (int gi = 0; gi < 2; ++gi) {
    const int g = t + gi * 256;
    const int r = g >> 2, slot = g & 3;
    const int s8 = slot ^ ((r >> 1) & 3);
    const float* src = X + (size_t)(blk * 128 + r) * DIMC + kb * 32 + s8 * 8;
    short8 vh;
#pragma unroll
    for (int j = 0; j < 8; ++j) vh[j] = (short)f2bf(src[j]);
    *(short8*)(out + ((size_t)blk * 8 + kb) * 4096 + g * 8) = vh;
  }
}

// ---------------------------------------------------------------------------
__global__ __launch_bounds__(256)
void vq_rownorm(const float* __restrict__ Z, float* __restrict__ anorm) {
  const int lane = threadIdx.x & 63;
  const int wv   = threadIdx.x >> 6;
  const int row  = blockIdx.x * 4 + wv;
  const float4 z4 = *(const float4*)(Z + (size_t)row * DIMC + lane * 4);
  double s = (double)z4.x * z4.x + (double)z4.y * z4.y +
             (double)z4.z * z4.z + (double)z4.w * z4.w;
#pragma unroll
  for (int off = 32; off > 0; off >>= 1) s += __shfl_down(s, off);
  if (lane == 0) anorm[row] = (float)s;
}

// ---------------------------------------------------------------------------
// Main: h-only bf16 MFMA GEMM (approx dot), 128x128 tiles, 16 KB LDS.
// Fused per-(row, colblock) exact top-2 of d = a - 2f*dot.  (validated r5/r6)
// ---------------------------------------------------------------------------
__global__ __launch_bounds__(256, 4)
void vq_mfma(const unsigned short* __restrict__ Zh, const unsigned short* __restrict__ Wh,
             const float* __restrict__ anorm, Part* __restrict__ partial) {
  __shared__ char lds[16384];          // A: [0,8K), B: [8K,16K)
  const int t = threadIdx.x, lane = t & 63, w = t >> 6;
  const int rb = blockIdx.x >> 5, cb = blockIdx.x & 31;
  const int q = lane >> 4, ml = lane & 15;
  const int wr = w >> 1, wc = w & 1;

  const unsigned short* src0 = (w < 2) ? Zh + (size_t)rb * 32768
                                       : Wh + (size_t)cb * 32768;
  const int half = w & 1;
  char* ldsdst = lds + (w >> 1) * 8192 + half * 4096;

  int aoff[4], boff[4];
#pragma unroll
  for (int i = 0; i < 4; ++i) {
    const int r = wr * 64 + i * 16 + ml;
    aoff[i] = (r * 4 + (q ^ ((r >> 1) & 3))) * 16;
    const int c = wc * 64 + i * 16 + ml;
    boff[i] = (c * 4 + (q ^ ((c >> 1) & 3))) * 16;
  }

  f32x4 acc[4][4];
#pragma unroll
  for (int i = 0; i < 4; ++i)
#pragma unroll
    for (int j = 0; j < 4; ++j) acc[i][j] = (f32x4){0.f, 0.f, 0.f, 0.f};

  for (int kb = 0; kb < 8; ++kb) {
    __syncthreads();
    const unsigned short* s = src0 + kb * 4096 + half * 2048 + lane * 8;
#pragma unroll
    for (int i = 0; i < 4; ++i)
      __builtin_amdgcn_global_load_lds((const AS1 void*)(s + i * 512),
                                       (AS3 void*)(ldsdst + i * 1024), 16, 0, 0);
    __syncthreads();
    short8 Ah[4], Bh[4];
#pragma unroll
    for (int i = 0; i < 4; ++i) {
      Ah[i] = *(const short8*)(lds +        aoff[i]);
      Bh[i] = *(const short8*)(lds + 8192 + boff[i]);
    }
#pragma unroll
    for (int i = 0; i < 4; ++i)
#pragma unroll
      for (int j = 0; j < 4; ++j)
        acc[i][j] = __builtin_amdgcn_mfma_f32_16x16x32_bf16(Ah[i], Bh[j], acc[i][j], 0, 0, 0);
  }

  __syncthreads();
  float* pd1 = (float*)lds;
  int*   pi1 = (int*)(lds + 1024);
  float* pd2 = (float*)(lds + 2048);
  const float INF = 3.4e38f;

#pragma unroll
  for (int i = 0; i < 4; ++i) {
#pragma unroll
    for (int r = 0; r < 4; ++r) {
      const int lr = i * 16 + q * 4 + r;
      const float am = anorm[rb * 128 + wr * 64 + lr];
      float d1m = INF, d2m = INF; int i1m = 0x7fffffff;
#pragma unroll
      for (int j = 0; j < 4; ++j) {
        const float d = am - 2.0f * acc[i][j][r];
        const int idx = cb * 128 + wc * 64 + j * 16 + ml;
        if (d < d1m || (d == d1m && idx < i1m)) { d2m = d1m; d1m = d; i1m = idx; }
        else d2m = fminf(d2m, d);
      }
#pragma unroll
      for (int mask = 1; mask < 16; mask <<= 1) {
        const float od1 = __shfl_xor(d1m, mask);
        const int   oi1 = __shfl_xor(i1m, mask);
        const float od2 = __shfl_xor(d2m, mask);
        if (od1 < d1m || (od1 == d1m && oi1 < i1m)) {
          d2m = fminf(d1m, od2); d1m = od1; i1m = oi1;
        } else d2m = fminf(d2m, od1);
      }
      if (ml == 0) { pd1[w * 64 + lr] = d1m; pi1[w * 64 + lr] = i1m; pd2[w * 64 + lr] = d2m; }
    }
  }
  __syncthreads();
  if (t < 128) {
    const int wrh = t >> 6, lr = t & 63;
    const int e0 = (wrh * 2 + 0) * 64 + lr, e1 = (wrh * 2 + 1) * 64 + lr;
    const float d1a = pd1[e0], d2a = pd2[e0]; const int i1a = pi1[e0];
    const float d1b = pd1[e1], d2b = pd2[e1]; const int i1b = pi1[e1];
    Part p;
    if (d1b < d1a || (d1b == d1a && i1b < i1a)) { p.d1 = d1b; p.i1 = i1b; p.d2 = fminf(d1a, d2b); }
    else                                        { p.d1 = d1a; p.i1 = i1a; p.d2 = fminf(d1b, d2a); }
    p.i2 = 0;
    const int row = rb * 128 + wrh * 64 + lr;
    partial[(size_t)row * 32 + cb] = p;
  }
}

// ---------------------------------------------------------------------------
// Merge partials per row: default index = approx argmin; flag rows whose
// approx top-2 gap is within WIN into a compact list.
// ---------------------------------------------------------------------------
__global__ __launch_bounds__(256)
void vq_merge(const Part* __restrict__ partial, int* __restrict__ idxbuf,
              int* __restrict__ list, int* __restrict__ cnt) {
  const int row = blockIdx.x * 256 + threadIdx.x;
  float g1 = 3.4e38f, g2 = 3.4e38f; int gi = 0x7fffffff;
  for (int cbk = 0; cbk < 32; ++cbk) {
    const Part p = partial[(size_t)row * 32 + cbk];
    if (p.d1 < g1 || (p.d1 == g1 && p.i1 < gi)) {
      g2 = fminf(fminf(g2, g1), p.d2); g1 = p.d1; gi = p.i1;
    } else g2 = fminf(g2, p.d1);
  }
  idxbuf[row] = gi;
  if (g2 - g1 <= WIN) { const int slot = atomicAdd(cnt, 1); list[slot] = row; }
}

// ---------------------------------------------------------------------------
// Exact np-semantics distance: ascending-dim fp32 fmaf chain (byte-identical
// to the chain validated rounds 2-6), d = fp32(a - 2f*dot).
// ---------------------------------------------------------------------------
__device__ __forceinline__ float exact_d(const float* __restrict__ Z,
                                         const float* __restrict__ W,
                                         int row, int c, float a) {
  const float* z = Z + (size_t)row * DIMC;
  const float* w = W + (size_t)c * DIMC;
  float dot = 0.f;
  for (int d0 = 0; d0 < DIMC; d0 += 4) {
    const float4 zv = *(const float4*)(z + d0);
    const float4 wv = *(const float4*)(w + d0);
    dot = fmaf(zv.x, wv.x, dot);
    dot = fmaf(zv.y, wv.y, dot);
    dot = fmaf(zv.z, wv.z, dot);
    dot = fmaf(zv.w, wv.w, dot);
  }
  return a - 2.0f * dot;
}

// ---------------------------------------------------------------------------
// Resolve: exact rescore of candidate codes for flagged rows only.
// One wave per flagged row. Candidates: each colblock's i1 with d1<=thr;
// full 128-code scan only where the block's exact 2nd-min d2<=thr (rare).
// Excluded codes are provably worse (d_ap > m+WIN covers 2*e); ties among
// rescored candidates resolved lexicographically (np argmin semantics).
// ---------------------------------------------------------------------------
__global__ __launch_bounds__(256)
void vq_resolve(const float* __restrict__ Z, const float* __restrict__ W,
                const float* __restrict__ anorm, const Part* __restrict__ partial,
                const int* __restrict__ list, const int* __restrict__ cnt,
                int* __restrict__ idxbuf) {
  const int lane = threadIdx.x & 63, wv = threadIdx.x >> 6;
  const int gw = blockIdx.x * 4 + wv, gstride = gridDim.x * 4;
  const int n = *cnt;
  const float INF = 3.4e38f;

  for (int ii = gw; ii < n; ii += gstride) {
    const int row = list[ii];
    const float a = anorm[row];
    float d1 = INF, d2 = INF; int i1 = 0x7fffffff;
    if (lane < 32) {
      const Part p = partial[(size_t)row * 32 + lane];
      d1 = p.d1; d2 = p.d2; i1 = p.i1;
    }
    float m = d1;
#pragma unroll
    for (int mask = 1; mask < 64; mask <<= 1) m = fminf(m, __shfl_xor(m, mask));
    const float thr = m + WIN;

    const bool scan   = (lane < 32) && (d2 <= thr);
    const bool single = (lane < 32) && !scan && (d1 <= thr);

    float bd = INF; int bi = 0x7fffffff;
    if (single) {
      const float d = exact_d(Z, W, row, i1, a);
      if (d < bd || (d == bd && i1 < bi)) { bd = d; bi = i1; }
    }
    unsigned long long msk = __ballot(scan);
    while (msk) {
      const int cbk = __ffsll(msk) - 1; msk &= msk - 1;
#pragma unroll
      for (int h = 0; h < 2; ++h) {
        const int c = cbk * 128 + h * 64 + lane;
        const float d = exact_d(Z, W, row, c, a);
        if (d < bd || (d == bd && c < bi)) { bd = d; bi = c; }
      }
    }
#pragma unroll
    for (int mask = 1; mask < 64; mask <<= 1) {
      const float od = __shfl_xor(bd, mask);
      const int   oi = __shfl_xor(bi, mask);
      if (od < bd || (od == bd && oi < bi)) { bd = od; bi = oi; }
    }
    if (lane == 0) idxbuf[row] = bi;
  }
}

// ---------------------------------------------------------------------------
__global__ __launch_bounds__(256)
void vq_select(const float* __restrict__ Z, const float* __restrict__ W,
               const int* __restrict__ idxbuf, float* __restrict__ zq_out,
               float* __restrict__ idx_out, double* __restrict__ loss_acc,
               int* __restrict__ hist) {
  __shared__ double sh[4];
  const int lane = threadIdx.x & 63;
  const int wv   = threadIdx.x >> 6;
  const int row  = blockIdx.x * 4 + wv;

  const int k = idxbuf[row];
  const float4 z4 = *(const float4*)(Z + (size_t)row * DIMC + lane * 4);
  const float4 w4 = *(const float4*)(W + (size_t)k   * DIMC + lane * 4);
  *(float4*)(zq_out + (size_t)row * DIMC + lane * 4) = w4;

  const double dx = (double)w4.x - (double)z4.x;
  const double dy = (double)w4.y - (double)z4.y;
  const double dz = (double)w4.z - (double)z4.z;
  const double dw = (double)w4.w - (double)z4.w;
  double l = dx * dx + dy * dy + dz * dz + dw * dw;
#pragma unroll
  for (int off = 32; off > 0; off >>= 1) l += __shfl_down(l, off);

  if (lane == 0) { sh[wv] = l; idx_out[row] = (float)k; atomicAdd(&hist[k], 1); }
  __syncthreads();
  if (threadIdx.x == 0) unsafeAtomicAdd(loss_acc, sh[0] + sh[1] + sh[2] + sh[3]);
}

__global__ __launch_bounds__(64)
void vq_final(const double* __restrict__ loss_acc, const int* __restrict__ hist,
              float* __restrict__ scal) {
  const int lane = threadIdx.x;
  double H = 0.0;
  for (int k = lane; k < KC; k += 64) {
    const double p = (double)hist[k] / (double)NROWS;
    H -= p * log(p + 1e-10);
  }
#pragma unroll
  for (int off = 32; off > 0; off >>= 1) H += __shfl_down(H, off);
  if (lane == 0) {
    scal[0] = (float)(loss_acc[0] * 1.25 / ((double)NROWS * (double)DIMC));
    scal[1] = (float)exp(H);
  }
}

// ---------------------------------------------------------------------------
extern "C" void kernel_launch(void* const* d_in, const int* in_sizes, int n_in,
                              void* d_out, int out_size, void* d_ws, size_t ws_size,
                              hipStream_t stream) {
  const float* Z = (const float*)d_in[0];
  const float* W = (const float*)d_in[1];
  float* out = (float*)d_out;
  float* zq_out  = out;
  float* idx_out = out + (size_t)NROWS * DIMC;
  float* scal    = idx_out + NROWS;

  char* ws = (char*)d_ws;
  double* loss_acc   = (double*)ws;                       // 8 B @0
  int*    cnt        = (int*)(ws + 8);
  int*    hist       = (int*)(ws + 1024);                 // 16 KB
  int*    idxbuf     = (int*)(ws + 32768);                // 128 KB
  float*  anorm      = (float*)(ws + 163840);             // 128 KB
  int*    list       = (int*)(ws + 294912);               // 128 KB
  Part*   partial    = (Part*)(ws + 1048576);             // 16 MB @ 1 MB
  unsigned short* Zh = (unsigned short*)(ws + 20971520);  // 16 MB @ 20 MB
  unsigned short* Wh = (unsigned short*)(ws + 37748736);  // 2 MB  @ 36 MB

  hipMemsetAsync(ws, 0, 17408, stream);                   // loss + cnt + hist
  vq_split<<<2048, 256, 0, stream>>>(Z, Zh);
  vq_split<<<256, 256, 0, stream>>>(W, Wh);
  vq_rownorm<<<NROWS / 4, 256, 0, stream>>>(Z, anorm);
  vq_mfma<<<8192, 256, 0, stream>>>(Zh, Wh, anorm, partial);
  vq_merge<<<128, 256, 0, stream>>>(partial, idxbuf, list, cnt);
  vq_resolve<<<2048, 256, 0, stream>>>(Z, W, anorm, partial, list, cnt, idxbuf);
  vq_select<<<NROWS / 4, 256, 0, stream>>>(Z, W, idxbuf, zq_out, idx_out, loss_acc, hist);
  vq_final<<<1, 64, 0, stream>>>(loss_acc, hist, scal);
}